// Round 1
// baseline (2025.148 us; speedup 1.0000x reference)
//
#include <hip/hip_runtime.h>

// Problem constants
#define BB 32
#define NN 1000
#define HH 256
#define DD 128
#define EE 512000
#define NB (BB * NN) // 32000

// Workspace layout (float offsets)
#define AGG_FLOATS (NB * HH)                 // 8,192,000 floats (32 MB)
#define DEGO_OFF (AGG_FLOATS)                // int[NB]
#define DEGI_OFF (AGG_FLOATS + NB)           // int[NB]
#define DSO_OFF (AGG_FLOATS + 2 * NB)        // float[NB]
#define DSI_OFF (AGG_FLOATS + 3 * NB)        // float[NB]
#define GATE_OFF (AGG_FLOATS + 4 * NB)       // float[4 * BB * HH]

// ---------------------------------------------------------------------------
// K1: degree histogram (int atomics, 2*E ops)
__global__ __launch_bounds__(256) void k_deg(const int* __restrict__ src,
                                             const int* __restrict__ dst,
                                             int* __restrict__ deg_out,
                                             int* __restrict__ deg_in) {
    int e = blockIdx.x * 256 + threadIdx.x;
    if (e < EE) {
        atomicAdd(&deg_out[src[e]], 1);
        atomicAdd(&deg_in[dst[e]], 1);
    }
}

// K2: degree -> rsqrt scales
__global__ __launch_bounds__(256) void k_scale(const int* __restrict__ deg_out,
                                               const int* __restrict__ deg_in,
                                               float* __restrict__ dso,
                                               float* __restrict__ dsi) {
    int v = blockIdx.x * 256 + threadIdx.x;
    if (v < NB) {
        dso[v] = rsqrtf((float)max(deg_out[v], 1));
        dsi[v] = rsqrtf((float)max(deg_in[v], 1));
    }
}

// K3: 4 input-gate projections x @ W* + b*  (tiny: 32x128x256 x4)
__global__ __launch_bounds__(256) void k_gates(
    const float* __restrict__ x, const float* __restrict__ Wi,
    const float* __restrict__ bi, const float* __restrict__ Wf,
    const float* __restrict__ bf_, const float* __restrict__ Wo,
    const float* __restrict__ bo, const float* __restrict__ Wc,
    const float* __restrict__ bc, float* __restrict__ gates) {
    int b = blockIdx.x;
    int j = threadIdx.x;
    __shared__ float xs[DD];
    if (j < DD) xs[j] = x[b * DD + j];
    __syncthreads();
    float ai = bi[j], af = bf_[j], ao = bo[j], ac = bc[j];
#pragma unroll 4
    for (int k = 0; k < DD; k++) {
        float xv = xs[k];
        ai += xv * Wi[k * HH + j];
        af += xv * Wf[k * HH + j];
        ao += xv * Wo[k * HH + j];
        ac += xv * Wc[k * HH + j];
    }
    gates[0 * BB * HH + b * HH + j] = ai;
    gates[1 * BB * HH + b * HH + j] = af;
    gates[2 * BB * HH + b * HH + j] = ao;
    gates[3 * BB * HH + b * HH + j] = ac;
}

// K4: edge scatter — one wave per edge; lane handles 4 consecutive floats.
// agg[dst] += h[src] * dso[src]   (131M fp32 atomics — expected bottleneck)
__global__ __launch_bounds__(256) void k_scatter(
    const float* __restrict__ h, const int* __restrict__ src,
    const int* __restrict__ dst, const float* __restrict__ dso,
    float* __restrict__ agg) {
    int gid = blockIdx.x * 256 + threadIdx.x;
    int e = gid >> 6;
    int lane = threadIdx.x & 63;
    if (e < EE) {
        int s = src[e];
        int d = dst[e];
        float sc = dso[s];
        float4 v = ((const float4*)(h + (size_t)s * HH))[lane];
        float* ap = agg + (size_t)d * HH + lane * 4;
        atomicAdd(ap + 0, v.x * sc);
        atomicAdd(ap + 1, v.y * sc);
        atomicAdd(ap + 2, v.z * sc);
        atomicAdd(ap + 3, v.w * sc);
    }
}

// K5: fused (agg * dsi) @ Wg + bg  -> LSTM elementwise -> h_t, c_t
// Tile = 32 rows x 256 cols; thread j owns column j for all 32 rows.
// h_conv row r depends only on agg row r, so the epilogue fuses cleanly and
// h_conv never touches HBM.
__global__ __launch_bounds__(256) void k_gemm_lstm(
    const float* __restrict__ agg, const float* __restrict__ dsi,
    const float* __restrict__ Wg, const float* __restrict__ bg,
    const float* __restrict__ gates, const float* __restrict__ c_prev,
    float* __restrict__ h_out, float* __restrict__ c_out) {
    __shared__ float4 as4[32][64]; // 32 rows x 256 floats (32 KB), float4-packed
    int t = threadIdx.x;
    int row0 = blockIdx.x * 32;

    // Stage + pre-scale by dsi[row]
    const float4* aggv = (const float4*)(agg + (size_t)row0 * HH);
#pragma unroll
    for (int p = 0; p < 8; p++) {
        int i = p * 256 + t;
        int r = i >> 6;
        int k4 = i & 63;
        float4 v = aggv[i];
        float sc = dsi[row0 + r];
        v.x *= sc; v.y *= sc; v.z *= sc; v.w *= sc;
        as4[r][k4] = v;
    }
    __syncthreads();

    int j = t;
    float acc[32];
    float bgj = bg[j];
#pragma unroll
    for (int r = 0; r < 32; r++) acc[r] = bgj;

    for (int k4 = 0; k4 < 64; k4++) {
        float w0 = Wg[(k4 * 4 + 0) * HH + j];
        float w1 = Wg[(k4 * 4 + 1) * HH + j];
        float w2 = Wg[(k4 * 4 + 2) * HH + j];
        float w3 = Wg[(k4 * 4 + 3) * HH + j];
#pragma unroll
        for (int r = 0; r < 32; r++) {
            float4 a = as4[r][k4]; // lane-uniform -> LDS broadcast, conflict-free
            acc[r] += a.x * w0 + a.y * w1 + a.z * w2 + a.w * w3;
        }
    }

    // LSTM epilogue
#pragma unroll 1
    for (int r = 0; r < 32; r++) {
        int node = row0 + r;
        int b = node / NN;
        float hc = acc[r];
        float pi = gates[0 * BB * HH + b * HH + j] + hc;
        float pf = gates[1 * BB * HH + b * HH + j] + hc;
        float po = gates[2 * BB * HH + b * HH + j] + hc;
        float pc = gates[3 * BB * HH + b * HH + j] + hc;
        float it = 1.f / (1.f + __expf(-pi));
        float ft = 1.f / (1.f + __expf(-pf));
        float ot = 1.f / (1.f + __expf(-po));
        float e2 = __expf(2.f * pc);
        float ctl = (e2 - 1.f) / (e2 + 1.f);
        float cp = c_prev[(size_t)node * HH + j];
        float ct = ft * cp + it * ctl;
        float e2c = __expf(2.f * ct);
        float th = (e2c - 1.f) / (e2c + 1.f);
        h_out[(size_t)node * HH + j] = ot * th;
        c_out[(size_t)node * HH + j] = ct;
    }
}

// ---------------------------------------------------------------------------
extern "C" void kernel_launch(void* const* d_in, const int* in_sizes, int n_in,
                              void* d_out, int out_size, void* d_ws,
                              size_t ws_size, hipStream_t stream) {
    const float* x = (const float*)d_in[0];
    const float* h_prev = (const float*)d_in[1];
    const float* c_prev = (const float*)d_in[2];
    const int* src = (const int*)d_in[3];
    const int* dst = (const int*)d_in[4];
    const float* Wi = (const float*)d_in[5];
    const float* bi = (const float*)d_in[6];
    const float* Wf = (const float*)d_in[7];
    const float* bf_ = (const float*)d_in[8];
    const float* Wo = (const float*)d_in[9];
    const float* bo = (const float*)d_in[10];
    const float* Wc = (const float*)d_in[11];
    const float* bc = (const float*)d_in[12];
    const float* Wg = (const float*)d_in[13];
    const float* bg = (const float*)d_in[14];

    float* ws = (float*)d_ws;
    float* agg = ws;
    int* deg_out = (int*)(ws + DEGO_OFF);
    int* deg_in = (int*)(ws + DEGI_OFF);
    float* dso = ws + DSO_OFF;
    float* dsi = ws + DSI_OFF;
    float* gates = ws + GATE_OFF;
    float* h_out = (float*)d_out;
    float* c_out = h_out + (size_t)NB * HH;

    // Zero agg + both degree arrays (ws is re-poisoned to 0xAA every call)
    hipMemsetAsync(d_ws, 0, (size_t)(AGG_FLOATS + 2 * NB) * 4, stream);

    k_deg<<<(EE + 255) / 256, 256, 0, stream>>>(src, dst, deg_out, deg_in);
    k_scale<<<(NB + 255) / 256, 256, 0, stream>>>(deg_out, deg_in, dso, dsi);
    k_gates<<<BB, 256, 0, stream>>>(x, Wi, bi, Wf, bf_, Wo, bo, Wc, bc, gates);
    k_scatter<<<EE / 4, 256, 0, stream>>>(h_prev, src, dst, dso, agg);
    k_gemm_lstm<<<NB / 32, 256, 0, stream>>>(agg, dsi, Wg, bg, gates, c_prev,
                                             h_out, c_out);
}

// Round 2
// 550.317 us; speedup vs baseline: 3.6800x; 3.6800x over previous
//
#include <hip/hip_runtime.h>

// Problem constants
#define BB 32
#define NN 1000
#define HH 256
#define DD 128
#define EE 512000
#define NB (BB * NN) // 32000

// Workspace layout (int/float offsets, 4B units)
#define DEGO_OFF 0                       // int[NB]
#define DEGI_OFF (NB)                    // int[NB]
#define ROWS_OFF (2 * NB)                // int[NB+1]
#define CURS_OFF (3 * NB + 8)            // int[NB]
#define SSRC_OFF (4 * NB + 8)            // int[EE]
#define DSO_OFF (4 * NB + 8 + EE)        // float[NB]
#define DSI_OFF (5 * NB + 8 + EE)        // float[NB]
#define GATE_OFF (6 * NB + 8 + EE)       // float[4*BB*HH]

// ---------------------------------------------------------------------------
// K1: degree histogram (1M int atomics)
__global__ __launch_bounds__(256) void k_deg(const int* __restrict__ src,
                                             const int* __restrict__ dst,
                                             int* __restrict__ deg_out,
                                             int* __restrict__ deg_in) {
    int e = blockIdx.x * 256 + threadIdx.x;
    if (e < EE) {
        atomicAdd(&deg_out[src[e]], 1);
        atomicAdd(&deg_in[dst[e]], 1);
    }
}

// K2: single-block exclusive prefix sum of deg_in -> row_start, cursor;
// also computes dso/dsi rsqrt scales.
#define SCAN_T 1024
#define CHUNK 32 // 1024*32 = 32768 >= NB
__global__ __launch_bounds__(SCAN_T) void k_scan(
    const int* __restrict__ deg_in, const int* __restrict__ deg_out,
    int* __restrict__ row_start, int* __restrict__ cursor,
    float* __restrict__ dso, float* __restrict__ dsi) {
    __shared__ int partial[SCAN_T];
    int t = threadIdx.x;
    int base = t * CHUNK;
    int s = 0;
#pragma unroll
    for (int i = 0; i < CHUNK; i++) {
        int idx = base + i;
        if (idx < NB) s += deg_in[idx];
    }
    partial[t] = s;
    __syncthreads();
    // Hillis-Steele inclusive scan over 1024 partials
    for (int off = 1; off < SCAN_T; off <<= 1) {
        int v = (t >= off) ? partial[t - off] : 0;
        __syncthreads();
        partial[t] += v;
        __syncthreads();
    }
    int run = (t == 0) ? 0 : partial[t - 1];
#pragma unroll 4
    for (int i = 0; i < CHUNK; i++) {
        int idx = base + i;
        if (idx < NB) {
            row_start[idx] = run;
            cursor[idx] = run;
            int d = deg_in[idx];
            run += d;
            dsi[idx] = rsqrtf((float)max(d, 1));
            dso[idx] = rsqrtf((float)max(deg_out[idx], 1));
        }
    }
    if (t == SCAN_T - 1) row_start[NB] = run;
}

// K3: counting-sort edges by dst (512k int atomics)
__global__ __launch_bounds__(256) void k_binsort(const int* __restrict__ src,
                                                 const int* __restrict__ dst,
                                                 int* __restrict__ cursor,
                                                 int* __restrict__ sorted_src) {
    int e = blockIdx.x * 256 + threadIdx.x;
    if (e < EE) {
        int pos = atomicAdd(&cursor[dst[e]], 1);
        sorted_src[pos] = src[e];
    }
}

// K4: 4 input-gate projections x @ W* + b*  (tiny: 32x128x256 x4)
__global__ __launch_bounds__(256) void k_gates(
    const float* __restrict__ x, const float* __restrict__ Wi,
    const float* __restrict__ bi, const float* __restrict__ Wf,
    const float* __restrict__ bf_, const float* __restrict__ Wo,
    const float* __restrict__ bo, const float* __restrict__ Wc,
    const float* __restrict__ bc, float* __restrict__ gates) {
    int b = blockIdx.x;
    int j = threadIdx.x;
    __shared__ float xs[DD];
    if (j < DD) xs[j] = x[b * DD + j];
    __syncthreads();
    float ai = bi[j], af = bf_[j], ao = bo[j], ac = bc[j];
#pragma unroll 4
    for (int k = 0; k < DD; k++) {
        float xv = xs[k];
        ai += xv * Wi[k * HH + j];
        af += xv * Wf[k * HH + j];
        ao += xv * Wo[k * HH + j];
        ac += xv * Wc[k * HH + j];
    }
    gates[0 * BB * HH + b * HH + j] = ai;
    gates[1 * BB * HH + b * HH + j] = af;
    gates[2 * BB * HH + b * HH + j] = ao;
    gates[3 * BB * HH + b * HH + j] = ac;
}

// K5: fused gather (CSR, atomic-free) + GEMM (agg@Wg+bg) + LSTM epilogue.
// Block = 256 threads = 4 waves handles 32 nodes.
// Phase 1: wave w gathers rows w*8..w*8+7 (lane holds float4 of the 256-wide
//          row) into LDS, pre-scaled by dso[src] and dsi[node].
// Phase 2: thread j owns column j for all 32 rows (LDS broadcast reads).
__global__ __launch_bounds__(256) void k_fused(
    const float* __restrict__ h, const int* __restrict__ sorted_src,
    const int* __restrict__ row_start, const float* __restrict__ dso,
    const float* __restrict__ dsi, const float* __restrict__ Wg,
    const float* __restrict__ bg, const float* __restrict__ gates,
    const float* __restrict__ c_prev, float* __restrict__ h_out,
    float* __restrict__ c_out) {
    __shared__ float4 as4[32][64]; // 32 rows x 256 floats (32 KB)
    int t = threadIdx.x;
    int lane = t & 63;
    int w = t >> 6;
    int row0 = blockIdx.x * 32;

    // Phase 1: gather
#pragma unroll 1
    for (int rr = 0; rr < 8; rr++) {
        int r = w * 8 + rr;
        int node = row0 + r;
        int beg = row_start[node];
        int end = row_start[node + 1];
        float4 acc = make_float4(0.f, 0.f, 0.f, 0.f);
        for (int e = beg; e < end; e++) {
            int s = sorted_src[e];
            float sc = dso[s];
            float4 v = ((const float4*)(h + (size_t)s * HH))[lane];
            acc.x += v.x * sc;
            acc.y += v.y * sc;
            acc.z += v.z * sc;
            acc.w += v.w * sc;
        }
        float si = dsi[node];
        acc.x *= si; acc.y *= si; acc.z *= si; acc.w *= si;
        as4[r][lane] = acc;
    }
    __syncthreads();

    // Phase 2: GEMM 32x256 @ 256x256 + LSTM
    int j = t;
    float acc[32];
    float bgj = bg[j];
#pragma unroll
    for (int r = 0; r < 32; r++) acc[r] = bgj;

    for (int k4 = 0; k4 < 64; k4++) {
        float w0 = Wg[(k4 * 4 + 0) * HH + j];
        float w1 = Wg[(k4 * 4 + 1) * HH + j];
        float w2 = Wg[(k4 * 4 + 2) * HH + j];
        float w3 = Wg[(k4 * 4 + 3) * HH + j];
#pragma unroll
        for (int r = 0; r < 32; r++) {
            float4 a = as4[r][k4]; // lane-uniform -> LDS broadcast
            acc[r] += a.x * w0 + a.y * w1 + a.z * w2 + a.w * w3;
        }
    }

#pragma unroll 1
    for (int r = 0; r < 32; r++) {
        int node = row0 + r;
        int b = node / NN;
        float hc = acc[r];
        float pi = gates[0 * BB * HH + b * HH + j] + hc;
        float pf = gates[1 * BB * HH + b * HH + j] + hc;
        float po = gates[2 * BB * HH + b * HH + j] + hc;
        float pc = gates[3 * BB * HH + b * HH + j] + hc;
        float it = 1.f / (1.f + __expf(-pi));
        float ft = 1.f / (1.f + __expf(-pf));
        float ot = 1.f / (1.f + __expf(-po));
        float e2 = __expf(2.f * pc);
        float ctl = (e2 - 1.f) / (e2 + 1.f);
        float cp = c_prev[(size_t)node * HH + j];
        float ct = ft * cp + it * ctl;
        float e2c = __expf(2.f * ct);
        float th = (e2c - 1.f) / (e2c + 1.f);
        h_out[(size_t)node * HH + j] = ot * th;
        c_out[(size_t)node * HH + j] = ct;
    }
}

// ---------------------------------------------------------------------------
extern "C" void kernel_launch(void* const* d_in, const int* in_sizes, int n_in,
                              void* d_out, int out_size, void* d_ws,
                              size_t ws_size, hipStream_t stream) {
    const float* x = (const float*)d_in[0];
    const float* h_prev = (const float*)d_in[1];
    const float* c_prev = (const float*)d_in[2];
    const int* src = (const int*)d_in[3];
    const int* dst = (const int*)d_in[4];
    const float* Wi = (const float*)d_in[5];
    const float* bi = (const float*)d_in[6];
    const float* Wf = (const float*)d_in[7];
    const float* bf_ = (const float*)d_in[8];
    const float* Wo = (const float*)d_in[9];
    const float* bo = (const float*)d_in[10];
    const float* Wc = (const float*)d_in[11];
    const float* bc = (const float*)d_in[12];
    const float* Wg = (const float*)d_in[13];
    const float* bg = (const float*)d_in[14];

    int* wsi = (int*)d_ws;
    float* wsf = (float*)d_ws;
    int* deg_out = wsi + DEGO_OFF;
    int* deg_in = wsi + DEGI_OFF;
    int* row_start = wsi + ROWS_OFF;
    int* cursor = wsi + CURS_OFF;
    int* sorted_src = wsi + SSRC_OFF;
    float* dso = wsf + DSO_OFF;
    float* dsi = wsf + DSI_OFF;
    float* gates = wsf + GATE_OFF;
    float* h_out = (float*)d_out;
    float* c_out = h_out + (size_t)NB * HH;

    // Zero only the degree counters (256 KB)
    hipMemsetAsync(deg_out, 0, (size_t)2 * NB * 4, stream);

    k_deg<<<(EE + 255) / 256, 256, 0, stream>>>(src, dst, deg_out, deg_in);
    k_scan<<<1, SCAN_T, 0, stream>>>(deg_in, deg_out, row_start, cursor, dso,
                                     dsi);
    k_binsort<<<(EE + 255) / 256, 256, 0, stream>>>(src, dst, cursor,
                                                    sorted_src);
    k_gates<<<BB, 256, 0, stream>>>(x, Wi, bi, Wf, bf_, Wo, bo, Wc, bc, gates);
    k_fused<<<NB / 32, 256, 0, stream>>>(h_prev, sorted_src, row_start, dso,
                                         dsi, Wg, bg, gates, c_prev, h_out,
                                         c_out);
}

// Round 3
// 429.718 us; speedup vs baseline: 4.7127x; 1.2806x over previous
//
#include <hip/hip_runtime.h>

// Problem constants
#define BB 32
#define NN 1000
#define HH 256
#define DD 128
#define EE 512000
#define NB (BB * NN) // 32000

// Workspace layout (dword offsets)
#define DEGO_OFF 0                        // int[NB]
#define DEGI_OFF (NB)                     // int[NB]
#define ROWS_OFF (2 * NB)                 // int[NB+1]
#define CURS_OFF (3 * NB + 8)             // int[NB]
#define SSRC_OFF (4 * NB + 8)             // int[EE]
#define DSO_OFF (4 * NB + 8 + EE)         // float[NB]
#define DSI_OFF (5 * NB + 8 + EE)         // float[NB]
#define GATE_OFF (6 * NB + 8 + EE)        // float[4*BB*HH]
#define WGB_OFF (GATE_OFF + 4 * BB * HH)  // bf16[HH*HH] = 32768 dwords
#define HW_OFF (WGB_OFF + (HH * HH) / 2)  // bf16[NB*HH] = 4096000 dwords

using bf16x8 = __attribute__((ext_vector_type(8))) short;
using f32x4 = __attribute__((ext_vector_type(4))) float;

__device__ inline unsigned short f2bf(float x) {  // RNE fp32 -> bf16
    unsigned u = __float_as_uint(x);
    return (unsigned short)((u + 0x7FFFu + ((u >> 16) & 1u)) >> 16);
}
__device__ inline float bf2f(unsigned short u) {
    return __uint_as_float(((unsigned)u) << 16);
}

// ---------------------------------------------------------------------------
// K1: degree histogram (1M int atomics)
__global__ __launch_bounds__(256) void k_deg(const int* __restrict__ src,
                                             const int* __restrict__ dst,
                                             int* __restrict__ deg_out,
                                             int* __restrict__ deg_in) {
    int e = blockIdx.x * 256 + threadIdx.x;
    if (e < EE) {
        atomicAdd(&deg_out[src[e]], 1);
        atomicAdd(&deg_in[dst[e]], 1);
    }
}

// K2: single-block prefix sum of deg_in -> row_start, cursor; rsqrt scales.
#define SCAN_T 1024
#define CHUNK 32
__global__ __launch_bounds__(SCAN_T) void k_scan(
    const int* __restrict__ deg_in, const int* __restrict__ deg_out,
    int* __restrict__ row_start, int* __restrict__ cursor,
    float* __restrict__ dso, float* __restrict__ dsi) {
    __shared__ int partial[SCAN_T];
    int t = threadIdx.x;
    int base = t * CHUNK;
    int s = 0;
#pragma unroll
    for (int i = 0; i < CHUNK; i++) {
        int idx = base + i;
        if (idx < NB) s += deg_in[idx];
    }
    partial[t] = s;
    __syncthreads();
    for (int off = 1; off < SCAN_T; off <<= 1) {
        int v = (t >= off) ? partial[t - off] : 0;
        __syncthreads();
        partial[t] += v;
        __syncthreads();
    }
    int run = (t == 0) ? 0 : partial[t - 1];
#pragma unroll 4
    for (int i = 0; i < CHUNK; i++) {
        int idx = base + i;
        if (idx < NB) {
            row_start[idx] = run;
            cursor[idx] = run;
            int d = deg_in[idx];
            run += d;
            dsi[idx] = rsqrtf((float)max(d, 1));
            dso[idx] = rsqrtf((float)max(deg_out[idx], 1));
        }
    }
    if (t == SCAN_T - 1) row_start[NB] = run;
}

// K3: counting-sort edges by dst (512k int atomics)
__global__ __launch_bounds__(256) void k_binsort(const int* __restrict__ src,
                                                 const int* __restrict__ dst,
                                                 int* __restrict__ cursor,
                                                 int* __restrict__ sorted_src) {
    int e = blockIdx.x * 256 + threadIdx.x;
    if (e < EE) {
        int pos = atomicAdd(&cursor[dst[e]], 1);
        sorted_src[pos] = src[e];
    }
}

// K4: 4 input-gate projections x @ W* + b*  (tiny)
__global__ __launch_bounds__(256) void k_gates(
    const float* __restrict__ x, const float* __restrict__ Wi,
    const float* __restrict__ bi, const float* __restrict__ Wf,
    const float* __restrict__ bf_, const float* __restrict__ Wo,
    const float* __restrict__ bo, const float* __restrict__ Wc,
    const float* __restrict__ bc, float* __restrict__ gates) {
    int b = blockIdx.x;
    int j = threadIdx.x;
    __shared__ float xs[DD];
    if (j < DD) xs[j] = x[b * DD + j];
    __syncthreads();
    float ai = bi[j], af = bf_[j], ao = bo[j], ac = bc[j];
#pragma unroll 4
    for (int k = 0; k < DD; k++) {
        float xv = xs[k];
        ai += xv * Wi[k * HH + j];
        af += xv * Wf[k * HH + j];
        ao += xv * Wo[k * HH + j];
        ac += xv * Wc[k * HH + j];
    }
    gates[0 * BB * HH + b * HH + j] = ai;
    gates[1 * BB * HH + b * HH + j] = af;
    gates[2 * BB * HH + b * HH + j] = ao;
    gates[3 * BB * HH + b * HH + j] = ac;
}

// K5: repack Wg (fp32 row-major) into bf16 MFMA-B-fragment order.
// Chunk c=(kk*16+nt)*64+lane holds 8 bf16: j -> Wg[kk*32+(lane>>4)*8+j][nt*16+(lane&15)]
__global__ __launch_bounds__(256) void k_wprep(const float* __restrict__ Wg,
                                               unsigned short* __restrict__ wgb) {
    int o = blockIdx.x * 256 + threadIdx.x; // 0..65535
    int j = o & 7;
    int c = o >> 3;
    int lane = c & 63;
    int nt = (c >> 6) & 15;
    int kk = c >> 10;
    int k = kk * 32 + (lane >> 4) * 8 + j;
    int n = nt * 16 + (lane & 15);
    wgb[o] = f2bf(Wg[k * HH + n]);
}

// K6: hW = (h_prev * dso[:,None]) @ Wg   via bf16 MFMA, output bf16.
// Block = 4 waves, each wave: 16 rows x 256 cols, K=256 (8 k-steps x 16 n-tiles).
__global__ __launch_bounds__(256) void k_hw(const float* __restrict__ h,
                                            const float* __restrict__ dso,
                                            const unsigned short* __restrict__ wgb,
                                            unsigned short* __restrict__ hw) {
    int t = threadIdx.x;
    int lane = t & 63;
    int w = t >> 6;
    int quad = lane >> 4;
    int mrow = lane & 15;
    int r0 = blockIdx.x * 64 + w * 16;
    int row = r0 + mrow;
    float sc = dso[row];

    f32x4 acc[16];
#pragma unroll
    for (int nt = 0; nt < 16; nt++) acc[nt] = (f32x4){0.f, 0.f, 0.f, 0.f};

#pragma unroll 1
    for (int kk = 0; kk < 8; kk++) {
        const float* ap = h + (size_t)row * HH + kk * 32 + quad * 8;
        float4 a0 = *(const float4*)ap;
        float4 a1 = *(const float4*)(ap + 4);
        bf16x8 af;
        af[0] = (short)f2bf(a0.x * sc);
        af[1] = (short)f2bf(a0.y * sc);
        af[2] = (short)f2bf(a0.z * sc);
        af[3] = (short)f2bf(a0.w * sc);
        af[4] = (short)f2bf(a1.x * sc);
        af[5] = (short)f2bf(a1.y * sc);
        af[6] = (short)f2bf(a1.z * sc);
        af[7] = (short)f2bf(a1.w * sc);
#pragma unroll
        for (int nt = 0; nt < 16; nt++) {
            bf16x8 bf =
                *(const bf16x8*)(wgb + (((kk * 16 + nt) * 64 + lane) << 3));
            acc[nt] =
                __builtin_amdgcn_mfma_f32_16x16x32_bf16(af, bf, acc[nt], 0, 0, 0);
        }
    }
    // C/D: col = nt*16 + (lane&15), row = r0 + quad*4 + reg
#pragma unroll
    for (int nt = 0; nt < 16; nt++) {
#pragma unroll
        for (int reg = 0; reg < 4; reg++) {
            hw[(size_t)(r0 + quad * 4 + reg) * HH + nt * 16 + mrow] =
                f2bf(acc[nt][reg]);
        }
    }
}

// K7: per-node gather of hW rows (CSR) -> h_conv -> LSTM epilogue.
// One wave per node; lane handles 4 consecutive columns.
__device__ inline void lstm1(float hc, float gi, float gf, float go, float gc,
                             float cp, float& ho, float& co) {
    float pi = gi + hc, pf = gf + hc, po = go + hc, pc = gc + hc;
    float it = 1.f / (1.f + __expf(-pi));
    float ft = 1.f / (1.f + __expf(-pf));
    float ot = 1.f / (1.f + __expf(-po));
    float e2 = __expf(2.f * pc);
    float ctl = (e2 - 1.f) / (e2 + 1.f);
    float ct = ft * cp + it * ctl;
    float e2c = __expf(2.f * ct);
    ho = ot * (e2c - 1.f) / (e2c + 1.f);
    co = ct;
}

__global__ __launch_bounds__(256) void k_out(
    const unsigned short* __restrict__ hw, const int* __restrict__ sorted_src,
    const int* __restrict__ row_start, const float* __restrict__ dsi,
    const float* __restrict__ bg, const float* __restrict__ gates,
    const float* __restrict__ c_prev, float* __restrict__ h_out,
    float* __restrict__ c_out) {
    int t = threadIdx.x;
    int lane = t & 63;
    int w = t >> 6;
    int node = blockIdx.x * 4 + w;
    int beg = row_start[node];
    int end = row_start[node + 1];
    int col = lane * 4;

    float ax = 0.f, ay = 0.f, az = 0.f, aw = 0.f;
    int e = beg;
    for (; e + 4 <= end; e += 4) {
        int s0 = sorted_src[e + 0];
        int s1 = sorted_src[e + 1];
        int s2 = sorted_src[e + 2];
        int s3 = sorted_src[e + 3];
        ushort4 q0 = *(const ushort4*)(hw + (size_t)s0 * HH + col);
        ushort4 q1 = *(const ushort4*)(hw + (size_t)s1 * HH + col);
        ushort4 q2 = *(const ushort4*)(hw + (size_t)s2 * HH + col);
        ushort4 q3 = *(const ushort4*)(hw + (size_t)s3 * HH + col);
        ax += bf2f(q0.x) + bf2f(q1.x) + bf2f(q2.x) + bf2f(q3.x);
        ay += bf2f(q0.y) + bf2f(q1.y) + bf2f(q2.y) + bf2f(q3.y);
        az += bf2f(q0.z) + bf2f(q1.z) + bf2f(q2.z) + bf2f(q3.z);
        aw += bf2f(q0.w) + bf2f(q1.w) + bf2f(q2.w) + bf2f(q3.w);
    }
    for (; e < end; e++) {
        int s = sorted_src[e];
        ushort4 q = *(const ushort4*)(hw + (size_t)s * HH + col);
        ax += bf2f(q.x);
        ay += bf2f(q.y);
        az += bf2f(q.z);
        aw += bf2f(q.w);
    }

    float si = dsi[node];
    int b = node / NN;
    float4 bgv = *(const float4*)(bg + col);
    float4 gi = *(const float4*)(gates + 0 * BB * HH + b * HH + col);
    float4 gf = *(const float4*)(gates + 1 * BB * HH + b * HH + col);
    float4 go = *(const float4*)(gates + 2 * BB * HH + b * HH + col);
    float4 gc = *(const float4*)(gates + 3 * BB * HH + b * HH + col);
    float4 cp = *(const float4*)(c_prev + (size_t)node * HH + col);

    float4 ho, co;
    lstm1(ax * si + bgv.x, gi.x, gf.x, go.x, gc.x, cp.x, ho.x, co.x);
    lstm1(ay * si + bgv.y, gi.y, gf.y, go.y, gc.y, cp.y, ho.y, co.y);
    lstm1(az * si + bgv.z, gi.z, gf.z, go.z, gc.z, cp.z, ho.z, co.z);
    lstm1(aw * si + bgv.w, gi.w, gf.w, go.w, gc.w, cp.w, ho.w, co.w);

    *(float4*)(h_out + (size_t)node * HH + col) = ho;
    *(float4*)(c_out + (size_t)node * HH + col) = co;
}

// ---------------------------------------------------------------------------
extern "C" void kernel_launch(void* const* d_in, const int* in_sizes, int n_in,
                              void* d_out, int out_size, void* d_ws,
                              size_t ws_size, hipStream_t stream) {
    const float* x = (const float*)d_in[0];
    const float* h_prev = (const float*)d_in[1];
    const float* c_prev = (const float*)d_in[2];
    const int* src = (const int*)d_in[3];
    const int* dst = (const int*)d_in[4];
    const float* Wi = (const float*)d_in[5];
    const float* bi = (const float*)d_in[6];
    const float* Wf = (const float*)d_in[7];
    const float* bf_ = (const float*)d_in[8];
    const float* Wo = (const float*)d_in[9];
    const float* bo = (const float*)d_in[10];
    const float* Wc = (const float*)d_in[11];
    const float* bc = (const float*)d_in[12];
    const float* Wg = (const float*)d_in[13];
    const float* bg = (const float*)d_in[14];

    int* wsi = (int*)d_ws;
    float* wsf = (float*)d_ws;
    int* deg_out = wsi + DEGO_OFF;
    int* deg_in = wsi + DEGI_OFF;
    int* row_start = wsi + ROWS_OFF;
    int* cursor = wsi + CURS_OFF;
    int* sorted_src = wsi + SSRC_OFF;
    float* dso = wsf + DSO_OFF;
    float* dsi = wsf + DSI_OFF;
    float* gates = wsf + GATE_OFF;
    unsigned short* wgb = (unsigned short*)(wsi + WGB_OFF);
    unsigned short* hw = (unsigned short*)(wsi + HW_OFF);
    float* h_out = (float*)d_out;
    float* c_out = h_out + (size_t)NB * HH;

    hipMemsetAsync(deg_out, 0, (size_t)2 * NB * 4, stream);

    k_deg<<<(EE + 255) / 256, 256, 0, stream>>>(src, dst, deg_out, deg_in);
    k_scan<<<1, SCAN_T, 0, stream>>>(deg_in, deg_out, row_start, cursor, dso,
                                     dsi);
    k_binsort<<<(EE + 255) / 256, 256, 0, stream>>>(src, dst, cursor,
                                                    sorted_src);
    k_wprep<<<(HH * HH) / 256, 256, 0, stream>>>(Wg, wgb);
    k_gates<<<BB, 256, 0, stream>>>(x, Wi, bi, Wf, bf_, Wo, bo, Wc, bc, gates);
    k_hw<<<NB / 64, 256, 0, stream>>>(h_prev, dso, wgb, hw);
    k_out<<<NB / 4, 256, 0, stream>>>(hw, sorted_src, row_start, dsi, bg,
                                      gates, c_prev, h_out, c_out);
}

// Round 4
// 306.963 us; speedup vs baseline: 6.5974x; 1.3999x over previous
//
#include <hip/hip_runtime.h>

// Problem constants
#define BB 32
#define NN 1000
#define HH 256
#define DD 128
#define EE 512000
#define NB (BB * NN) // 32000
#define SCAN_B 125   // 125 * 256 == NB

// Workspace layout (dword offsets)
#define DEGO_OFF 0                        // int[NB]
#define DEGI_OFF (NB)                     // int[NB]
#define ROWS_OFF (2 * NB)                 // int[NB+1]
#define CURS_OFF (3 * NB + 8)             // int[NB]
#define SSRC_OFF (4 * NB + 8)             // int[EE]
#define DSO_OFF (4 * NB + 8 + EE)         // float[NB]
#define DSI_OFF (5 * NB + 8 + EE)         // float[NB]
#define GATE_OFF (6 * NB + 8 + EE)        // float[4*BB*HH]
#define LOCE_OFF (GATE_OFF + 4 * BB * HH) // int[NB] per-elem exclusive (in-block)
#define BSUM_OFF (LOCE_OFF + NB)          // int[128]
#define BOFF_OFF (BSUM_OFF + 128)         // int[128]
#define WGB_OFF (BOFF_OFF + 128)          // bf16[HH*HH] = 32768 dwords
#define HW_OFF (WGB_OFF + (HH * HH) / 2)  // bf16[NB*HH] = 4096000 dwords

using bf16x8 = __attribute__((ext_vector_type(8))) short;
using f32x4 = __attribute__((ext_vector_type(4))) float;

__device__ inline unsigned short f2bf(float x) {  // RNE fp32 -> bf16
    unsigned u = __float_as_uint(x);
    return (unsigned short)((u + 0x7FFFu + ((u >> 16) & 1u)) >> 16);
}
__device__ inline float bf2f(unsigned short u) {
    return __uint_as_float(((unsigned)u) << 16);
}

// ---------------------------------------------------------------------------
// K1: degree histogram (1M int atomics)
__global__ __launch_bounds__(256) void k_deg(const int* __restrict__ src,
                                             const int* __restrict__ dst,
                                             int* __restrict__ deg_out,
                                             int* __restrict__ deg_in) {
    int e = blockIdx.x * 256 + threadIdx.x;
    if (e < EE) {
        atomicAdd(&deg_out[src[e]], 1);
        atomicAdd(&deg_in[dst[e]], 1);
    }
}

// K2a: per-block exclusive scan of deg_in; emit block sums; fold rsqrt scales.
__global__ __launch_bounds__(256) void k_scan1(
    const int* __restrict__ deg_in, const int* __restrict__ deg_out,
    int* __restrict__ loce, int* __restrict__ bsum, float* __restrict__ dso,
    float* __restrict__ dsi) {
    __shared__ int sm[256];
    int b = blockIdx.x, t = threadIdx.x;
    int idx = b * 256 + t;
    int d = deg_in[idx];
    sm[t] = d;
    __syncthreads();
    int total_add;
    for (int off = 1; off < 256; off <<= 1) {
        total_add = (t >= off) ? sm[t - off] : 0;
        __syncthreads();
        sm[t] += total_add;
        __syncthreads();
    }
    loce[idx] = sm[t] - d; // exclusive within block
    if (t == 255) bsum[b] = sm[255];
    dsi[idx] = rsqrtf((float)max(d, 1));
    dso[idx] = rsqrtf((float)max(deg_out[idx], 1));
}

// K2b: single small block scans the 125 block sums (exclusive).
__global__ __launch_bounds__(128) void k_scan2(const int* __restrict__ bsum,
                                               int* __restrict__ boff) {
    __shared__ int sm[128];
    int t = threadIdx.x;
    int v = (t < SCAN_B) ? bsum[t] : 0;
    sm[t] = v;
    __syncthreads();
    for (int off = 1; off < 128; off <<= 1) {
        int u = (t >= off) ? sm[t - off] : 0;
        __syncthreads();
        sm[t] += u;
        __syncthreads();
    }
    boff[t] = sm[t] - v; // exclusive
}

// K2c: combine -> row_start, cursor.
__global__ __launch_bounds__(256) void k_scan3(const int* __restrict__ loce,
                                               const int* __restrict__ boff,
                                               int* __restrict__ row_start,
                                               int* __restrict__ cursor) {
    int b = blockIdx.x, t = threadIdx.x;
    int idx = b * 256 + t;
    int e = loce[idx] + boff[b];
    row_start[idx] = e;
    cursor[idx] = e;
    if (idx == 0) row_start[NB] = EE;
}

// K3: counting-sort edges by dst (512k int atomics)
__global__ __launch_bounds__(256) void k_binsort(const int* __restrict__ src,
                                                 const int* __restrict__ dst,
                                                 int* __restrict__ cursor,
                                                 int* __restrict__ sorted_src) {
    int e = blockIdx.x * 256 + threadIdx.x;
    if (e < EE) {
        int pos = atomicAdd(&cursor[dst[e]], 1);
        sorted_src[pos] = src[e];
    }
}

// K4: 4 input-gate projections x @ W* + b*  (tiny)
__global__ __launch_bounds__(256) void k_gates(
    const float* __restrict__ x, const float* __restrict__ Wi,
    const float* __restrict__ bi, const float* __restrict__ Wf,
    const float* __restrict__ bf_, const float* __restrict__ Wo,
    const float* __restrict__ bo, const float* __restrict__ Wc,
    const float* __restrict__ bc, float* __restrict__ gates) {
    int b = blockIdx.x;
    int j = threadIdx.x;
    __shared__ float xs[DD];
    if (j < DD) xs[j] = x[b * DD + j];
    __syncthreads();
    float ai = bi[j], af = bf_[j], ao = bo[j], ac = bc[j];
#pragma unroll 4
    for (int k = 0; k < DD; k++) {
        float xv = xs[k];
        ai += xv * Wi[k * HH + j];
        af += xv * Wf[k * HH + j];
        ao += xv * Wo[k * HH + j];
        ac += xv * Wc[k * HH + j];
    }
    gates[0 * BB * HH + b * HH + j] = ai;
    gates[1 * BB * HH + b * HH + j] = af;
    gates[2 * BB * HH + b * HH + j] = ao;
    gates[3 * BB * HH + b * HH + j] = ac;
}

// K5: repack Wg (fp32 row-major) into bf16 MFMA-B-fragment order.
__global__ __launch_bounds__(256) void k_wprep(const float* __restrict__ Wg,
                                               unsigned short* __restrict__ wgb) {
    int o = blockIdx.x * 256 + threadIdx.x; // 0..65535
    int j = o & 7;
    int c = o >> 3;
    int lane = c & 63;
    int nt = (c >> 6) & 15;
    int kk = c >> 10;
    int k = kk * 32 + (lane >> 4) * 8 + j;
    int n = nt * 16 + (lane & 15);
    wgb[o] = f2bf(Wg[k * HH + n]);
}

// K6: hW = (h_prev * dso[:,None]) @ Wg   via bf16 MFMA, output bf16.
__global__ __launch_bounds__(256) void k_hw(const float* __restrict__ h,
                                            const float* __restrict__ dso,
                                            const unsigned short* __restrict__ wgb,
                                            unsigned short* __restrict__ hw) {
    int t = threadIdx.x;
    int lane = t & 63;
    int w = t >> 6;
    int quad = lane >> 4;
    int mrow = lane & 15;
    int r0 = blockIdx.x * 64 + w * 16;
    int row = r0 + mrow;
    float sc = dso[row];

    f32x4 acc[16];
#pragma unroll
    for (int nt = 0; nt < 16; nt++) acc[nt] = (f32x4){0.f, 0.f, 0.f, 0.f};

#pragma unroll 1
    for (int kk = 0; kk < 8; kk++) {
        const float* ap = h + (size_t)row * HH + kk * 32 + quad * 8;
        float4 a0 = *(const float4*)ap;
        float4 a1 = *(const float4*)(ap + 4);
        bf16x8 af;
        af[0] = (short)f2bf(a0.x * sc);
        af[1] = (short)f2bf(a0.y * sc);
        af[2] = (short)f2bf(a0.z * sc);
        af[3] = (short)f2bf(a0.w * sc);
        af[4] = (short)f2bf(a1.x * sc);
        af[5] = (short)f2bf(a1.y * sc);
        af[6] = (short)f2bf(a1.z * sc);
        af[7] = (short)f2bf(a1.w * sc);
#pragma unroll
        for (int nt = 0; nt < 16; nt++) {
            bf16x8 bf =
                *(const bf16x8*)(wgb + (((kk * 16 + nt) * 64 + lane) << 3));
            acc[nt] =
                __builtin_amdgcn_mfma_f32_16x16x32_bf16(af, bf, acc[nt], 0, 0, 0);
        }
    }
#pragma unroll
    for (int nt = 0; nt < 16; nt++) {
#pragma unroll
        for (int reg = 0; reg < 4; reg++) {
            hw[(size_t)(r0 + quad * 4 + reg) * HH + nt * 16 + mrow] =
                f2bf(acc[nt][reg]);
        }
    }
}

// K7: per-node gather of hW rows (CSR) -> h_conv -> LSTM epilogue.
__device__ inline void lstm1(float hc, float gi, float gf, float go, float gc,
                             float cp, float& ho, float& co) {
    float pi = gi + hc, pf = gf + hc, po = go + hc, pc = gc + hc;
    float it = 1.f / (1.f + __expf(-pi));
    float ft = 1.f / (1.f + __expf(-pf));
    float ot = 1.f / (1.f + __expf(-po));
    float e2 = __expf(2.f * pc);
    float ctl = (e2 - 1.f) / (e2 + 1.f);
    float ct = ft * cp + it * ctl;
    float e2c = __expf(2.f * ct);
    ho = ot * (e2c - 1.f) / (e2c + 1.f);
    co = ct;
}

__global__ __launch_bounds__(256) void k_out(
    const unsigned short* __restrict__ hw, const int* __restrict__ sorted_src,
    const int* __restrict__ row_start, const float* __restrict__ dsi,
    const float* __restrict__ bg, const float* __restrict__ gates,
    const float* __restrict__ c_prev, float* __restrict__ h_out,
    float* __restrict__ c_out) {
    int t = threadIdx.x;
    int lane = t & 63;
    int w = t >> 6;
    int node = blockIdx.x * 4 + w;
    int beg = row_start[node];
    int end = row_start[node + 1];
    int col = lane * 4;

    float ax = 0.f, ay = 0.f, az = 0.f, aw = 0.f;
    int e = beg;
    for (; e + 4 <= end; e += 4) {
        int s0 = sorted_src[e + 0];
        int s1 = sorted_src[e + 1];
        int s2 = sorted_src[e + 2];
        int s3 = sorted_src[e + 3];
        ushort4 q0 = *(const ushort4*)(hw + (size_t)s0 * HH + col);
        ushort4 q1 = *(const ushort4*)(hw + (size_t)s1 * HH + col);
        ushort4 q2 = *(const ushort4*)(hw + (size_t)s2 * HH + col);
        ushort4 q3 = *(const ushort4*)(hw + (size_t)s3 * HH + col);
        ax += bf2f(q0.x) + bf2f(q1.x) + bf2f(q2.x) + bf2f(q3.x);
        ay += bf2f(q0.y) + bf2f(q1.y) + bf2f(q2.y) + bf2f(q3.y);
        az += bf2f(q0.z) + bf2f(q1.z) + bf2f(q2.z) + bf2f(q3.z);
        aw += bf2f(q0.w) + bf2f(q1.w) + bf2f(q2.w) + bf2f(q3.w);
    }
    for (; e < end; e++) {
        int s = sorted_src[e];
        ushort4 q = *(const ushort4*)(hw + (size_t)s * HH + col);
        ax += bf2f(q.x);
        ay += bf2f(q.y);
        az += bf2f(q.z);
        aw += bf2f(q.w);
    }

    float si = dsi[node];
    int b = node / NN;
    float4 bgv = *(const float4*)(bg + col);
    float4 gi = *(const float4*)(gates + 0 * BB * HH + b * HH + col);
    float4 gf = *(const float4*)(gates + 1 * BB * HH + b * HH + col);
    float4 go = *(const float4*)(gates + 2 * BB * HH + b * HH + col);
    float4 gc = *(const float4*)(gates + 3 * BB * HH + b * HH + col);
    float4 cp = *(const float4*)(c_prev + (size_t)node * HH + col);

    float4 ho, co;
    lstm1(ax * si + bgv.x, gi.x, gf.x, go.x, gc.x, cp.x, ho.x, co.x);
    lstm1(ay * si + bgv.y, gi.y, gf.y, go.y, gc.y, cp.y, ho.y, co.y);
    lstm1(az * si + bgv.z, gi.z, gf.z, go.z, gc.z, cp.z, ho.z, co.z);
    lstm1(aw * si + bgv.w, gi.w, gf.w, go.w, gc.w, cp.w, ho.w, co.w);

    *(float4*)(h_out + (size_t)node * HH + col) = ho;
    *(float4*)(c_out + (size_t)node * HH + col) = co;
}

// ---------------------------------------------------------------------------
extern "C" void kernel_launch(void* const* d_in, const int* in_sizes, int n_in,
                              void* d_out, int out_size, void* d_ws,
                              size_t ws_size, hipStream_t stream) {
    const float* x = (const float*)d_in[0];
    const float* h_prev = (const float*)d_in[1];
    const float* c_prev = (const float*)d_in[2];
    const int* src = (const int*)d_in[3];
    const int* dst = (const int*)d_in[4];
    const float* Wi = (const float*)d_in[5];
    const float* bi = (const float*)d_in[6];
    const float* Wf = (const float*)d_in[7];
    const float* bf_ = (const float*)d_in[8];
    const float* Wo = (const float*)d_in[9];
    const float* bo = (const float*)d_in[10];
    const float* Wc = (const float*)d_in[11];
    const float* bc = (const float*)d_in[12];
    const float* Wg = (const float*)d_in[13];
    const float* bg = (const float*)d_in[14];

    int* wsi = (int*)d_ws;
    float* wsf = (float*)d_ws;
    int* deg_out = wsi + DEGO_OFF;
    int* deg_in = wsi + DEGI_OFF;
    int* row_start = wsi + ROWS_OFF;
    int* cursor = wsi + CURS_OFF;
    int* sorted_src = wsi + SSRC_OFF;
    float* dso = wsf + DSO_OFF;
    float* dsi = wsf + DSI_OFF;
    float* gates = wsf + GATE_OFF;
    int* loce = wsi + LOCE_OFF;
    int* bsum = wsi + BSUM_OFF;
    int* boff = wsi + BOFF_OFF;
    unsigned short* wgb = (unsigned short*)(wsi + WGB_OFF);
    unsigned short* hw = (unsigned short*)(wsi + HW_OFF);
    float* h_out = (float*)d_out;
    float* c_out = h_out + (size_t)NB * HH;

    hipMemsetAsync(deg_out, 0, (size_t)2 * NB * 4, stream);

    k_deg<<<(EE + 255) / 256, 256, 0, stream>>>(src, dst, deg_out, deg_in);
    k_scan1<<<SCAN_B, 256, 0, stream>>>(deg_in, deg_out, loce, bsum, dso, dsi);
    k_scan2<<<1, 128, 0, stream>>>(bsum, boff);
    k_scan3<<<SCAN_B, 256, 0, stream>>>(loce, boff, row_start, cursor);
    k_binsort<<<(EE + 255) / 256, 256, 0, stream>>>(src, dst, cursor,
                                                    sorted_src);
    k_wprep<<<(HH * HH) / 256, 256, 0, stream>>>(Wg, wgb);
    k_gates<<<BB, 256, 0, stream>>>(x, Wi, bi, Wf, bf_, Wo, bo, Wc, bc, gates);
    k_hw<<<NB / 64, 256, 0, stream>>>(h_prev, dso, wgb, hw);
    k_out<<<NB / 4, 256, 0, stream>>>(hw, sorted_src, row_start, dsi, bg,
                                      gates, c_prev, h_out, c_out);
}